// Round 9
// baseline (414.843 us; speedup 1.0000x reference)
//
#include <hip/hip_runtime.h>
#include <hip/hip_bf16.h>

// Problem constants (fixed by setup_inputs)
constexpr int TDIM = 16384;
constexpr int DIN  = 4096;
constexpr int DOUT = 4096;
constexpr int RNK  = 32;
constexpr float EPSF = 1e-8f;

using i32x4 = __attribute__((ext_vector_type(4))) int;

// ---------------------------------------------------------------------------
// Kernel 1: weight_eff = W + loraB @ loraA  -> per-row absmax -> int8 quantize
// (unchanged from round 2)
// ---------------------------------------------------------------------------
__global__ __launch_bounds__(256)
void wquant_kernel(const float* __restrict__ W,
                   const float* __restrict__ Amat,   // [32, 4096]
                   const float* __restrict__ Bmat,   // [4096, 32]
                   float* __restrict__ a_w,          // [4096]
                   signed char* __restrict__ qw)     // [4096, 4096]
{
    const int tid = threadIdx.x;
    const int o0  = blockIdx.x * 4;

    __shared__ float Bsh[4][32];
    __shared__ float red[4][4];
    __shared__ float awsh[4];

    if (tid < 128) {
        int r = tid >> 5, c = tid & 31;
        Bsh[r][c] = Bmat[(size_t)(o0 + r) * RNK + c];
    }
    __syncthreads();

    float4 acc[4][4];
    #pragma unroll
    for (int r = 0; r < 4; ++r)
        #pragma unroll
        for (int c = 0; c < 4; ++c)
            acc[r][c] = *(const float4*)(W + (size_t)(o0 + r) * DIN + c * 1024 + tid * 4);

    #pragma unroll 4
    for (int k = 0; k < RNK; ++k) {
        float4 a[4];
        #pragma unroll
        for (int c = 0; c < 4; ++c)
            a[c] = *(const float4*)(Amat + (size_t)k * DIN + c * 1024 + tid * 4);
        #pragma unroll
        for (int r = 0; r < 4; ++r) {
            const float b = Bsh[r][k];
            #pragma unroll
            for (int c = 0; c < 4; ++c) {
                acc[r][c].x += b * a[c].x; acc[r][c].y += b * a[c].y;
                acc[r][c].z += b * a[c].z; acc[r][c].w += b * a[c].w;
            }
        }
    }

    const int wid = tid >> 6;
    #pragma unroll
    for (int r = 0; r < 4; ++r) {
        float m = 0.f;
        #pragma unroll
        for (int c = 0; c < 4; ++c) {
            float4 v = acc[r][c];
            m = fmaxf(m, fmaxf(fmaxf(fabsf(v.x), fabsf(v.y)),
                               fmaxf(fabsf(v.z), fabsf(v.w))));
        }
        for (int off = 1; off < 64; off <<= 1)
            m = fmaxf(m, __shfl_xor(m, off));
        if ((tid & 63) == 0) red[wid][r] = m;
    }
    __syncthreads();
    if (tid < 4) {
        float m = fmaxf(fmaxf(red[0][tid], red[1][tid]),
                        fmaxf(red[2][tid], red[3][tid]));
        float aw = m + EPSF;
        awsh[tid] = aw;
        a_w[o0 + tid] = aw;
    }
    __syncthreads();

    #pragma unroll
    for (int r = 0; r < 4; ++r) {
        const float aw = awsh[r];
        #pragma unroll
        for (int c = 0; c < 4; ++c) {
            float4 v = acc[r][c];
            int q0 = __float2int_rn((v.x / aw) * 127.0f);
            int q1 = __float2int_rn((v.y / aw) * 127.0f);
            int q2 = __float2int_rn((v.z / aw) * 127.0f);
            int q3 = __float2int_rn((v.w / aw) * 127.0f);
            unsigned int packed = (q0 & 0xff) | ((q1 & 0xff) << 8) |
                                  ((q2 & 0xff) << 16) | ((q3 & 0xff) << 24);
            *(unsigned int*)(qw + (size_t)(o0 + r) * DIN + c * 1024 + tid * 4) = packed;
        }
    }
}

// ---------------------------------------------------------------------------
// Kernel 2: x quantize (unchanged from round 2 — coalesced)
// ---------------------------------------------------------------------------
__global__ __launch_bounds__(256)
void xquant_kernel(const float* __restrict__ x,
                   const float* __restrict__ axp,
                   unsigned int* __restrict__ qx)
{
    const float inv = 1.0f / fmaxf(axp[0], EPSF);
    const size_t base = (size_t)blockIdx.x * 1024 + threadIdx.x;
    const float4* xv = (const float4*)x;

    float4 v[4];
    #pragma unroll
    for (int j = 0; j < 4; ++j)
        v[j] = xv[base + j * 256];

    #pragma unroll
    for (int j = 0; j < 4; ++j) {
        int q0 = __float2int_rn(fminf(fmaxf(v[j].x * inv, -1.f), 1.f) * 127.0f);
        int q1 = __float2int_rn(fminf(fmaxf(v[j].y * inv, -1.f), 1.f) * 127.0f);
        int q2 = __float2int_rn(fminf(fmaxf(v[j].z * inv, -1.f), 1.f) * 127.0f);
        int q3 = __float2int_rn(fminf(fmaxf(v[j].w * inv, -1.f), 1.f) * 127.0f);
        qx[base + j * 256] = (q0 & 0xff) | ((q1 & 0xff) << 8) |
                             ((q2 & 0xff) << 16) | ((q3 & 0xff) << 24);
    }
}

// ---------------------------------------------------------------------------
// Kernel 3 (V4): 256x256 i8 GEMM, 1 barrier/K-tile, per-cluster read groups
// software-pipelined one cluster ahead.
// Cluster order: C0=(mh0,k0) C1=(mh1,k0) C2=(mh0,k1) C3=(mh1,k1); B-frags
// reused within a k-step. Read groups G0={bf0,af0}(8) G1={af2}(4)
// G2={bf1,af1}(8) G3={af3}(4); G(i+1) issued before/under MFMA-i so each
// group's LDS drain hides under the previous 16-MFMA cluster. Counted lgkm
// gates retire exactly one group: (4)/(8)/(4)/(0).
// A dbuf (64KB) + B tbuf (96KB) = 160 KiB LDS. vmcnt invariant as V3:
// tile-start outstanding = B(t+1)x4; +8 issued; tile-end vmcnt(4) retires
// B(t+1)+A(t+1), floats B(t+2).
// ---------------------------------------------------------------------------
__global__ __launch_bounds__(512, 2)
void gemm8v4_kernel(const signed char* __restrict__ qx,
                    const signed char* __restrict__ qw,
                    const float* __restrict__ a_w,
                    const float* __restrict__ bias,
                    const float* __restrict__ axp,
                    float* __restrict__ out)
{
    __shared__ signed char As[2 * 256 * 128];   // 64 KB
    __shared__ signed char Bs[3 * 256 * 128];   // 96 KB -> 160 KiB total (max)

    const int tid  = threadIdx.x;
    const int lane = tid & 63;
    const int wid  = tid >> 6;
    const int wm   = wid >> 2;
    const int wn   = wid & 3;

    const int bid = blockIdx.x;
    const int nb  = bid & 15;
    const int mb  = bid >> 4;

    const size_t K = DIN;
    constexpr int NT = DIN / 128;   // 32 K-tiles

    const int srow8 = tid >> 3;
    const int sblk  = ((tid & 7) ^ ((tid >> 4) & 7)) << 4;
    const signed char* aPanel = qx + (size_t)(mb * 256) * K;
    const signed char* bPanel = qw + (size_t)(nb * 256) * K;

    const int r15  = lane & 15;
    const int blk  = lane >> 4;
    const int key  = (r15 >> 1) & 7;
    const int sw0  = (blk ^ key) << 4;
    const int sw1  = ((blk ^ key) ^ 4) << 4;
    const int aRd0 = (wm * 128 + r15) * 128 + sw0;
    const int aRd1 = (wm * 128 + r15) * 128 + sw1;
    const int bRd0 = (wn * 64 + r15) * 128 + sw0;
    const int bRd1 = (wn * 64 + r15) * 128 + sw1;

    i32x4 acc[8][4];
    #pragma unroll
    for (int m = 0; m < 8; ++m)
        #pragma unroll
        for (int n = 0; n < 4; ++n) acc[m][n] = i32x4{0, 0, 0, 0};

#define STAGE_U(panel, ldsArr, T, h, pb)                                       \
    {                                                                          \
        const int tc = (T) < NT ? (T) : (NT - 1);                              \
        const size_t kOff = (size_t)tc * 128;                                  \
        _Pragma("unroll")                                                      \
        for (int j = 0; j < 2; ++j) {                                          \
            __builtin_amdgcn_global_load_lds(                                  \
                (const __attribute__((address_space(1))) unsigned int*)        \
                    ((panel) + (size_t)((h) * 128 + j * 64 + srow8) * K + kOff + sblk), \
                (__attribute__((address_space(3))) unsigned int*)              \
                    ((ldsArr) + (pb) * 32768 + (h) * 16384 + j * 8192 + tid * 16), \
                16, 0, 0);                                                     \
        }                                                                      \
    }

    // ---- prologue: B(0)->B0, A(0)->A0, B(1)->B1 (12 loads); vmcnt(4)
    //      retires B(0),A(0); leaves B(1) outstanding (= loop invariant) ----
    STAGE_U(bPanel, Bs, 0, 0, 0); STAGE_U(bPanel, Bs, 0, 1, 0);
    STAGE_U(aPanel, As, 0, 0, 0); STAGE_U(aPanel, As, 0, 1, 0);
    STAGE_U(bPanel, Bs, 1, 0, 1); STAGE_U(bPanel, Bs, 1, 1, 1);
    asm volatile("s_waitcnt vmcnt(4)" ::: "memory");
    __builtin_amdgcn_sched_barrier(0);
    __builtin_amdgcn_s_barrier();

    int q = 0;   // B read buffer = t % 3
    for (int t = 0; t < NT; ++t) {
        const int p  = t & 1;
        const int qc = (q == 0) ? 2 : q - 1;   // (t+2) % 3
        const signed char* Ab = As + p * 32768;
        const signed char* Bb = Bs + q * 32768;
        i32x4 bf0[4], bf1[4], af0[4], af1[4], af2[4], af3[4];

        // ---- G0: bf0, af0 (8 reads) ----
        #pragma unroll
        for (int n = 0; n < 4; ++n) bf0[n] = *(const i32x4*)(Bb + bRd0 + n * 2048);
        #pragma unroll
        for (int m = 0; m < 4; ++m) af0[m] = *(const i32x4*)(Ab + aRd0 + m * 2048);
        __builtin_amdgcn_sched_barrier(0);
        // ---- G1: af2 (4 reads) ----
        #pragma unroll
        for (int m = 0; m < 4; ++m) af2[m] = *(const i32x4*)(Ab + aRd0 + 8192 + m * 2048);
        __builtin_amdgcn_sched_barrier(0);

        // ---- all staging DMA (vmcnt only; targets fenced by last barrier) ----
        STAGE_U(aPanel, As, t + 1, 0, p ^ 1);
        STAGE_U(aPanel, As, t + 1, 1, p ^ 1);
        STAGE_U(bPanel, Bs, t + 2, 0, qc);
        STAGE_U(bPanel, Bs, t + 2, 1, qc);

        // ---- MFMA-0 (mh0,k0): needs G0 only -> lgkm(4) (G1 may pend) ----
        asm volatile("s_waitcnt lgkmcnt(4)" ::: "memory");
        __builtin_amdgcn_sched_barrier(0);
        __builtin_amdgcn_s_setprio(1);
        #pragma unroll
        for (int m = 0; m < 4; ++m)
            #pragma unroll
            for (int n = 0; n < 4; ++n)
                acc[m][n] = __builtin_amdgcn_mfma_i32_16x16x64_i8(af0[m], bf0[n], acc[m][n], 0, 0, 0);
        __builtin_amdgcn_s_setprio(0);
        __builtin_amdgcn_sched_barrier(0);

        // ---- G2: bf1, af1 (8 reads) — drain under MFMA-1 ----
        #pragma unroll
        for (int n = 0; n < 4; ++n) bf1[n] = *(const i32x4*)(Bb + bRd1 + n * 2048);
        #pragma unroll
        for (int m = 0; m < 4; ++m) af1[m] = *(const i32x4*)(Ab + aRd1 + m * 2048);
        __builtin_amdgcn_sched_barrier(0);

        // ---- MFMA-1 (mh1,k0): needs G1 -> lgkm(8) (G2 pends) ----
        asm volatile("s_waitcnt lgkmcnt(8)" ::: "memory");
        __builtin_amdgcn_sched_barrier(0);
        __builtin_amdgcn_s_setprio(1);
        #pragma unroll
        for (int m = 0; m < 4; ++m)
            #pragma unroll
            for (int n = 0; n < 4; ++n)
                acc[m + 4][n] = __builtin_amdgcn_mfma_i32_16x16x64_i8(af2[m], bf0[n], acc[m + 4][n], 0, 0, 0);
        __builtin_amdgcn_s_setprio(0);
        __builtin_amdgcn_sched_barrier(0);

        // ---- G3: af3 (4 reads) — drain under MFMA-2 ----
        #pragma unroll
        for (int m = 0; m < 4; ++m) af3[m] = *(const i32x4*)(Ab + aRd1 + 8192 + m * 2048);
        __builtin_amdgcn_sched_barrier(0);

        // ---- MFMA-2 (mh0,k1): needs G2 -> lgkm(4) (G3 pends) ----
        asm volatile("s_waitcnt lgkmcnt(4)" ::: "memory");
        __builtin_amdgcn_sched_barrier(0);
        __builtin_amdgcn_s_setprio(1);
        #pragma unroll
        for (int m = 0; m < 4; ++m)
            #pragma unroll
            for (int n = 0; n < 4; ++n)
                acc[m][n] = __builtin_amdgcn_mfma_i32_16x16x64_i8(af1[m], bf1[n], acc[m][n], 0, 0, 0);
        __builtin_amdgcn_s_setprio(0);
        __builtin_amdgcn_sched_barrier(0);

        // ---- MFMA-3 (mh1,k1): needs G3 -> lgkm(0) ----
        asm volatile("s_waitcnt lgkmcnt(0)" ::: "memory");
        __builtin_amdgcn_sched_barrier(0);
        __builtin_amdgcn_s_setprio(1);
        #pragma unroll
        for (int m = 0; m < 4; ++m)
            #pragma unroll
            for (int n = 0; n < 4; ++n)
                acc[m + 4][n] = __builtin_amdgcn_mfma_i32_16x16x64_i8(af3[m], bf1[n], acc[m + 4][n], 0, 0, 0);
        __builtin_amdgcn_s_setprio(0);
        __builtin_amdgcn_sched_barrier(0);

        // ---- tile end: A(t+1),B(t+1) resident; B(t+2) stays in flight ----
        asm volatile("s_waitcnt vmcnt(4)" ::: "memory");
        __builtin_amdgcn_sched_barrier(0);
        __builtin_amdgcn_s_barrier();

        q = (q == 2) ? 0 : q + 1;
    }
#undef STAGE_U

    asm volatile("s_waitcnt vmcnt(0)" ::: "memory");

    // ---- epilogue: C/D layout col=lane&15, row=(lane>>4)*4+reg ----
    const float ax = fmaxf(axp[0], EPSF);
    #pragma unroll
    for (int n = 0; n < 4; ++n) {
        const int o = nb * 256 + wn * 64 + n * 16 + r15;
        const float scale = ax * a_w[o] * (1.0f / 16129.0f);
        const float bs = bias[o];
        #pragma unroll
        for (int m = 0; m < 8; ++m) {
            const int t0 = mb * 256 + wm * 128 + m * 16 + (blk << 2);
            float* op = out + (size_t)t0 * DOUT + o;
            #pragma unroll
            for (int r = 0; r < 4; ++r)
                op[(size_t)r * DOUT] = (float)acc[m][n][r] * scale + bs;
        }
    }
}

// ---------------------------------------------------------------------------
extern "C" void kernel_launch(void* const* d_in, const int* in_sizes, int n_in,
                              void* d_out, int out_size, void* d_ws, size_t ws_size,
                              hipStream_t stream)
{
    const float* x    = (const float*)d_in[0];
    const float* W    = (const float*)d_in[1];
    const float* lA   = (const float*)d_in[2];
    const float* lB   = (const float*)d_in[3];
    const float* bias = (const float*)d_in[4];
    const float* ax   = (const float*)d_in[5];
    float* out        = (float*)d_out;

    // workspace: qx (64MB) | qw (16MB) | a_w (16KB)
    signed char* qx = (signed char*)d_ws;
    signed char* qw = qx + (size_t)TDIM * DIN;
    float* a_w      = (float*)(qw + (size_t)DOUT * DIN);

    wquant_kernel<<<DOUT / 4, 256, 0, stream>>>(W, lA, lB, a_w, qw);

    const int xblocks = (int)(((size_t)TDIM * DIN) / (16 * 256));  // 16384
    xquant_kernel<<<xblocks, 256, 0, stream>>>(x, ax, (unsigned int*)qx);

    gemm8v4_kernel<<<(TDIM / 256) * (DOUT / 256), 512, 0, stream>>>(
        qx, qw, a_w, bias, ax, out);
}

// Round 10
// 394.140 us; speedup vs baseline: 1.0525x; 1.0525x over previous
//
#include <hip/hip_runtime.h>
#include <hip/hip_bf16.h>

// Problem constants (fixed by setup_inputs)
constexpr int TDIM = 16384;
constexpr int DIN  = 4096;
constexpr int DOUT = 4096;
constexpr int RNK  = 32;
constexpr float EPSF = 1e-8f;

constexpr int WQ_BLOCKS = DOUT / 4;                                  // 1024
constexpr int XQ_BLOCKS = (int)(((size_t)TDIM * DIN) / (32 * 256));  // 8192

using i32x4 = __attribute__((ext_vector_type(4))) int;

// ---------------------------------------------------------------------------
// Kernel 1 (FUSED): wquant (blocks 0..1023, issued FIRST so it overlaps the
// xquant sweep) + xquant (blocks 1024..9215). Bodies bit-identical to the
// proven round-2 kernels; xquant widened to 32 floats/thread (8 float4 loads
// in flight) so reduced occupancy (merged VGPR ~90) still saturates HBM.
// ---------------------------------------------------------------------------
__global__ __launch_bounds__(256)
void quant_fused_kernel(const float* __restrict__ x,
                        const float* __restrict__ W,
                        const float* __restrict__ Amat,   // [32, 4096]
                        const float* __restrict__ Bmat,   // [4096, 32]
                        const float* __restrict__ axp,
                        float* __restrict__ a_w,          // [4096]
                        signed char* __restrict__ qw,     // [4096, 4096]
                        unsigned int* __restrict__ qx)    // [16384*4096/4]
{
    const int tid = threadIdx.x;

    if (blockIdx.x < WQ_BLOCKS) {
        // ==================== wquant path (round-2 body) ====================
        const int o0 = blockIdx.x * 4;

        __shared__ float Bsh[4][32];
        __shared__ float red[4][4];
        __shared__ float awsh[4];

        if (tid < 128) {
            int r = tid >> 5, c = tid & 31;
            Bsh[r][c] = Bmat[(size_t)(o0 + r) * RNK + c];
        }
        __syncthreads();

        float4 acc[4][4];
        #pragma unroll
        for (int r = 0; r < 4; ++r)
            #pragma unroll
            for (int c = 0; c < 4; ++c)
                acc[r][c] = *(const float4*)(W + (size_t)(o0 + r) * DIN + c * 1024 + tid * 4);

        #pragma unroll 4
        for (int k = 0; k < RNK; ++k) {
            float4 a[4];
            #pragma unroll
            for (int c = 0; c < 4; ++c)
                a[c] = *(const float4*)(Amat + (size_t)k * DIN + c * 1024 + tid * 4);
            #pragma unroll
            for (int r = 0; r < 4; ++r) {
                const float b = Bsh[r][k];
                #pragma unroll
                for (int c = 0; c < 4; ++c) {
                    acc[r][c].x += b * a[c].x; acc[r][c].y += b * a[c].y;
                    acc[r][c].z += b * a[c].z; acc[r][c].w += b * a[c].w;
                }
            }
        }

        const int wid = tid >> 6;
        #pragma unroll
        for (int r = 0; r < 4; ++r) {
            float m = 0.f;
            #pragma unroll
            for (int c = 0; c < 4; ++c) {
                float4 v = acc[r][c];
                m = fmaxf(m, fmaxf(fmaxf(fabsf(v.x), fabsf(v.y)),
                                   fmaxf(fabsf(v.z), fabsf(v.w))));
            }
            for (int off = 1; off < 64; off <<= 1)
                m = fmaxf(m, __shfl_xor(m, off));
            if ((tid & 63) == 0) red[wid][r] = m;
        }
        __syncthreads();
        if (tid < 4) {
            float m = fmaxf(fmaxf(red[0][tid], red[1][tid]),
                            fmaxf(red[2][tid], red[3][tid]));
            float aw = m + EPSF;
            awsh[tid] = aw;
            a_w[o0 + tid] = aw;
        }
        __syncthreads();

        #pragma unroll
        for (int r = 0; r < 4; ++r) {
            const float aw = awsh[r];
            #pragma unroll
            for (int c = 0; c < 4; ++c) {
                float4 v = acc[r][c];
                int q0 = __float2int_rn((v.x / aw) * 127.0f);
                int q1 = __float2int_rn((v.y / aw) * 127.0f);
                int q2 = __float2int_rn((v.z / aw) * 127.0f);
                int q3 = __float2int_rn((v.w / aw) * 127.0f);
                unsigned int packed = (q0 & 0xff) | ((q1 & 0xff) << 8) |
                                      ((q2 & 0xff) << 16) | ((q3 & 0xff) << 24);
                *(unsigned int*)(qw + (size_t)(o0 + r) * DIN + c * 1024 + tid * 4) = packed;
            }
        }
    } else {
        // ==================== xquant path (coalesced, 32 floats/thread) =====
        const int xbid = blockIdx.x - WQ_BLOCKS;
        const float inv = 1.0f / fmaxf(axp[0], EPSF);
        const size_t base = (size_t)xbid * 2048 + tid;   // float4 index
        const float4* xv = (const float4*)x;

        float4 v[8];
        #pragma unroll
        for (int j = 0; j < 8; ++j)
            v[j] = xv[base + j * 256];

        #pragma unroll
        for (int j = 0; j < 8; ++j) {
            int q0 = __float2int_rn(fminf(fmaxf(v[j].x * inv, -1.f), 1.f) * 127.0f);
            int q1 = __float2int_rn(fminf(fmaxf(v[j].y * inv, -1.f), 1.f) * 127.0f);
            int q2 = __float2int_rn(fminf(fmaxf(v[j].z * inv, -1.f), 1.f) * 127.0f);
            int q3 = __float2int_rn(fminf(fmaxf(v[j].w * inv, -1.f), 1.f) * 127.0f);
            qx[base + j * 256] = (q0 & 0xff) | ((q1 & 0xff) << 8) |
                                 ((q2 & 0xff) << 16) | ((q3 & 0xff) << 24);
        }
    }
}

// ---------------------------------------------------------------------------
// Kernel 3 (V3, round-8 verbatim): 256x256 i8 GEMM, ONE barrier per K-tile.
// A dbuf (64KB) + B tbuf (96KB) = 160 KiB LDS. Per tile: 24 ds_reads issued
// as one wait-ordered burst, 8 DMA loads (A(t+1), B(t+2)), 4 MFMA clusters
// gated lgkmcnt(15)/(4)/none/(0), tile-end vmcnt(4) + single s_barrier.
// Proven: 271 us, MfmaUtil 45.7%, 0 bank conflicts.
// ---------------------------------------------------------------------------
__global__ __launch_bounds__(512, 2)
void gemm8v3_kernel(const signed char* __restrict__ qx,
                    const signed char* __restrict__ qw,
                    const float* __restrict__ a_w,
                    const float* __restrict__ bias,
                    const float* __restrict__ axp,
                    float* __restrict__ out)
{
    __shared__ signed char As[2 * 256 * 128];   // 64 KB
    __shared__ signed char Bs[3 * 256 * 128];   // 96 KB

    const int tid  = threadIdx.x;
    const int lane = tid & 63;
    const int wid  = tid >> 6;
    const int wm   = wid >> 2;
    const int wn   = wid & 3;

    const int bid = blockIdx.x;
    const int nb  = bid & 15;
    const int mb  = bid >> 4;

    const size_t K = DIN;
    constexpr int NT = DIN / 128;   // 32 K-tiles

    const int srow8 = tid >> 3;
    const int sblk  = ((tid & 7) ^ ((tid >> 4) & 7)) << 4;
    const signed char* aPanel = qx + (size_t)(mb * 256) * K;
    const signed char* bPanel = qw + (size_t)(nb * 256) * K;

    const int r15  = lane & 15;
    const int blk  = lane >> 4;
    const int key  = (r15 >> 1) & 7;
    const int sw0  = (blk ^ key) << 4;
    const int sw1  = ((blk ^ key) ^ 4) << 4;
    const int aRd0 = (wm * 128 + r15) * 128 + sw0;
    const int aRd1 = (wm * 128 + r15) * 128 + sw1;
    const int bRd0 = (wn * 64 + r15) * 128 + sw0;
    const int bRd1 = (wn * 64 + r15) * 128 + sw1;

    i32x4 acc[8][4];
    #pragma unroll
    for (int m = 0; m < 8; ++m)
        #pragma unroll
        for (int n = 0; n < 4; ++n) acc[m][n] = i32x4{0, 0, 0, 0};

#define STAGE_U(panel, ldsArr, T, h, pb)                                       \
    {                                                                          \
        const int tc = (T) < NT ? (T) : (NT - 1);                              \
        const size_t kOff = (size_t)tc * 128;                                  \
        _Pragma("unroll")                                                      \
        for (int j = 0; j < 2; ++j) {                                          \
            __builtin_amdgcn_global_load_lds(                                  \
                (const __attribute__((address_space(1))) unsigned int*)        \
                    ((panel) + (size_t)((h) * 128 + j * 64 + srow8) * K + kOff + sblk), \
                (__attribute__((address_space(3))) unsigned int*)              \
                    ((ldsArr) + (pb) * 32768 + (h) * 16384 + j * 8192 + tid * 16), \
                16, 0, 0);                                                     \
        }                                                                      \
    }

    // ---- prologue: B(0)->B0, A(0)->A0, B(1)->B1 (12 loads); vmcnt(4)
    //      retires B(0),A(0); leaves B(1) outstanding (= loop invariant) ----
    STAGE_U(bPanel, Bs, 0, 0, 0); STAGE_U(bPanel, Bs, 0, 1, 0);
    STAGE_U(aPanel, As, 0, 0, 0); STAGE_U(aPanel, As, 0, 1, 0);
    STAGE_U(bPanel, Bs, 1, 0, 1); STAGE_U(bPanel, Bs, 1, 1, 1);
    asm volatile("s_waitcnt vmcnt(4)" ::: "memory");
    __builtin_amdgcn_sched_barrier(0);
    __builtin_amdgcn_s_barrier();

    int q = 0;   // B read buffer = t % 3
    for (int t = 0; t < NT; ++t) {
        const int p  = t & 1;
        const int qc = (q == 0) ? 2 : q - 1;   // (t+2) % 3
        const signed char* Ab = As + p * 32768;
        const signed char* Bb = Bs + q * 32768;
        i32x4 bf0[4], bf1[4], af0[4], af1[4], af2[4], af3[4];

        // ---- issue all 24 ds_reads in wait-order (groups pinned) ----
        #pragma unroll
        for (int n = 0; n < 4; ++n) bf0[n] = *(const i32x4*)(Bb + bRd0 + n * 2048);
        #pragma unroll
        for (int m = 0; m < 4; ++m) af0[m] = *(const i32x4*)(Ab + aRd0 + m * 2048);
        __builtin_amdgcn_sched_barrier(0);   // group 1: bf0,af0 (8)
        #pragma unroll
        for (int m = 0; m < 4; ++m) af2[m] = *(const i32x4*)(Ab + aRd0 + 8192 + m * 2048);
        __builtin_amdgcn_sched_barrier(0);   // group 2: af2 (12)
        #pragma unroll
        for (int n = 0; n < 4; ++n) bf1[n] = *(const i32x4*)(Bb + bRd1 + n * 2048);
        #pragma unroll
        for (int m = 0; m < 4; ++m) af1[m] = *(const i32x4*)(Ab + aRd1 + m * 2048);
        __builtin_amdgcn_sched_barrier(0);   // group 3: bf1,af1 (20)
        #pragma unroll
        for (int m = 0; m < 4; ++m) af3[m] = *(const i32x4*)(Ab + aRd1 + 8192 + m * 2048);
        __builtin_amdgcn_sched_barrier(0);   // group 4: af3 (24)

        // ---- issue ALL staging DMA now (targets fenced by last barrier) ----
        STAGE_U(aPanel, As, t + 1, 0, p ^ 1);
        STAGE_U(aPanel, As, t + 1, 1, p ^ 1);
        STAGE_U(bPanel, Bs, t + 2, 0, qc);
        STAGE_U(bPanel, Bs, t + 2, 1, qc);

        // ---- MFMA-0: needs bf0,af0 (oldest 8 of 24) ----
        asm volatile("s_waitcnt lgkmcnt(15)" ::: "memory");
        __builtin_amdgcn_sched_barrier(0);
        __builtin_amdgcn_s_setprio(1);
        #pragma unroll
        for (int m = 0; m < 4; ++m)
            #pragma unroll
            for (int n = 0; n < 4; ++n)
                acc[m][n] = __builtin_amdgcn_mfma_i32_16x16x64_i8(af0[m], bf0[n], acc[m][n], 0, 0, 0);
        __builtin_amdgcn_s_setprio(0);

        // ---- MFMA-1: needs through af1 (oldest 20) ----
        asm volatile("s_waitcnt lgkmcnt(4)" ::: "memory");
        __builtin_amdgcn_sched_barrier(0);
        __builtin_amdgcn_s_setprio(1);
        #pragma unroll
        for (int m = 0; m < 4; ++m)
            #pragma unroll
            for (int n = 0; n < 4; ++n)
                acc[m][n] = __builtin_amdgcn_mfma_i32_16x16x64_i8(af1[m], bf1[n], acc[m][n], 0, 0, 0);
        __builtin_amdgcn_s_setprio(0);
        __builtin_amdgcn_sched_barrier(0);

        // ---- MFMA-2: af2 (pos 9-12) already covered by lgkm(4) ----
        __builtin_amdgcn_s_setprio(1);
        #pragma unroll
        for (int m = 0; m < 4; ++m)
            #pragma unroll
            for (int n = 0; n < 4; ++n)
                acc[m + 4][n] = __builtin_amdgcn_mfma_i32_16x16x64_i8(af2[m], bf0[n], acc[m + 4][n], 0, 0, 0);
        __builtin_amdgcn_s_setprio(0);

        // ---- MFMA-3: needs af3 -> drain ----
        asm volatile("s_waitcnt lgkmcnt(0)" ::: "memory");
        __builtin_amdgcn_sched_barrier(0);
        __builtin_amdgcn_s_setprio(1);
        #pragma unroll
        for (int m = 0; m < 4; ++m)
            #pragma unroll
            for (int n = 0; n < 4; ++n)
                acc[m + 4][n] = __builtin_amdgcn_mfma_i32_16x16x64_i8(af3[m], bf1[n], acc[m + 4][n], 0, 0, 0);
        __builtin_amdgcn_s_setprio(0);
        __builtin_amdgcn_sched_barrier(0);

        // ---- tile end: A(t+1),B(t+1) resident; B(t+2) stays in flight ----
        asm volatile("s_waitcnt vmcnt(4)" ::: "memory");
        __builtin_amdgcn_sched_barrier(0);
        __builtin_amdgcn_s_barrier();

        q = (q == 2) ? 0 : q + 1;
    }
#undef STAGE_U

    asm volatile("s_waitcnt vmcnt(0)" ::: "memory");

    // ---- epilogue: C/D layout col=lane&15, row=(lane>>4)*4+reg ----
    const float ax = fmaxf(axp[0], EPSF);
    #pragma unroll
    for (int n = 0; n < 4; ++n) {
        const int o = nb * 256 + wn * 64 + n * 16 + r15;
        const float scale = ax * a_w[o] * (1.0f / 16129.0f);
        const float bs = bias[o];
        #pragma unroll
        for (int m = 0; m < 8; ++m) {
            const int t0 = mb * 256 + wm * 128 + m * 16 + (blk << 2);
            float* op = out + (size_t)t0 * DOUT + o;
            #pragma unroll
            for (int r = 0; r < 4; ++r)
                op[(size_t)r * DOUT] = (float)acc[m][n][r] * scale + bs;
        }
    }
}

// ---------------------------------------------------------------------------
extern "C" void kernel_launch(void* const* d_in, const int* in_sizes, int n_in,
                              void* d_out, int out_size, void* d_ws, size_t ws_size,
                              hipStream_t stream)
{
    const float* x    = (const float*)d_in[0];
    const float* W    = (const float*)d_in[1];
    const float* lA   = (const float*)d_in[2];
    const float* lB   = (const float*)d_in[3];
    const float* bias = (const float*)d_in[4];
    const float* ax   = (const float*)d_in[5];
    float* out        = (float*)d_out;

    // workspace: qx (64MB) | qw (16MB) | a_w (16KB)
    signed char* qx = (signed char*)d_ws;
    signed char* qw = qx + (size_t)TDIM * DIN;
    float* a_w      = (float*)(qw + (size_t)DOUT * DIN);

    quant_fused_kernel<<<WQ_BLOCKS + XQ_BLOCKS, 256, 0, stream>>>(
        x, W, lA, lB, ax, a_w, qw, (unsigned int*)qx);

    gemm8v3_kernel<<<(TDIM / 256) * (DOUT / 256), 512, 0, stream>>>(
        qx, qw, a_w, bias, ax, out);
}